// Round 8
// baseline (456.669 us; speedup 1.0000x reference)
//
#include <hip/hip_runtime.h>
#include <hip/hip_bf16.h>
#include <stdint.h>

// ---------- types ----------
typedef __bf16 bf16_t;
typedef __attribute__((ext_vector_type(8))) __bf16 bf16x8;   // MFMA A/B frag (4 VGPR)
typedef __attribute__((ext_vector_type(4))) float floatx4;   // 16x16 C frag
typedef __attribute__((ext_vector_type(16))) float f32x16;   // 32x32 C frag

typedef __attribute__((address_space(1))) const unsigned int gu32_t;
typedef __attribute__((address_space(3))) unsigned int lu32_t;

#define SL2E 0.12753102149f  // log2(e)/sqrt(128), folded into Q at projection

// async global->LDS, 16B per lane; LDS dest = wave-uniform base + lane*16
__device__ __forceinline__ void async16(const void* g, void* l) {
    __builtin_amdgcn_global_load_lds((gu32_t*)g, (lu32_t*)l, 16, 0, 0);
}

__device__ __forceinline__ uint32_t pack2(float lo, float hi) {
    union { bf16_t h[2]; uint32_t u; } cv;
    cv.h[0] = (bf16_t)lo; cv.h[1] = (bf16_t)hi;
    return cv.u;
}

// ---------- fp32 -> bf16: x + 4 weights in ONE dispatch ----------
// dst layout is contiguous [xb | wq | wk | wv | wo], so dst off = b*2048.
__global__ __launch_bounds__(256) void cvt_all(const float* __restrict__ x,
                                               const float* __restrict__ w0,
                                               const float* __restrict__ w1,
                                               const float* __restrict__ w2,
                                               const float* __restrict__ w3,
                                               bf16_t* __restrict__ out) {
    int b = blockIdx.x;
    const float* in;
    if (b < 4096) {
        in = x + (size_t)b * 2048;
    } else {
        int t = b - 4096;
        const float* wsrc[4] = {w0, w1, w2, w3};
        in = wsrc[t >> 11] + (size_t)(t & 2047) * 2048;
    }
    bf16_t* o = out + (size_t)b * 2048;
    int i = threadIdx.x * 8;
    float4 a = *(const float4*)(in + i);
    float4 c = *(const float4*)(in + i + 4);
    bf16x8 v;
    v[0] = (bf16_t)a.x; v[1] = (bf16_t)a.y; v[2] = (bf16_t)a.z; v[3] = (bf16_t)a.w;
    v[4] = (bf16_t)c.x; v[5] = (bf16_t)c.y; v[6] = (bf16_t)c.z; v[7] = (bf16_t)c.w;
    *(bf16x8*)(o + i) = v;
}

// ---------- fused QK + V^T projection, one 1536-block dispatch ----------
// bid < 1024: QK tile -> QKb[row][col], col<2048 is Q (scaled by SL2E, bias
// folded), else K (+bk). bid >= 1024: V^T tile -> Vtb[feat][token] (+bv[row]).
// Both outputs have ldc = 4096, K = 2048. Same m97-style inner loop.
__global__ __launch_bounds__(256) void gemm_qkv(const bf16_t* __restrict__ xb,
                                                const bf16_t* __restrict__ wqk,
                                                const bf16_t* __restrict__ wv,
                                                const float* __restrict__ bq,
                                                const float* __restrict__ bk,
                                                const float* __restrict__ bv,
                                                bf16_t* __restrict__ QKb,
                                                bf16_t* __restrict__ Vtb) {
    __shared__ bf16_t As[128 * 64];
    __shared__ bf16_t Bs[128 * 64];
    const int tid = threadIdx.x;
    const int wave = tid >> 6, lane = tid & 63;
    const int quad = lane >> 4, l16 = lane & 15;
    const int wm = (wave >> 1) * 64, wn = (wave & 1) * 64;

    const int bid = blockIdx.x;
    const bool vmode = bid >= 1024;
    int tm, tn;
    const bf16_t *A, *B;
    bf16_t* Cb;
    if (!vmode) { tm = (bid & 31) * 128; tn = (bid >> 5) * 128; A = xb; B = wqk; Cb = QKb; }
    else { int vb = bid - 1024; tm = (vb & 15) * 128; tn = (vb >> 4) * 128; A = wv; B = xb; Cb = Vtb; }
    const int K = 2048, ldc = 4096;

    floatx4 acc[4][4];
#pragma unroll
    for (int i = 0; i < 4; ++i)
#pragma unroll
        for (int j = 0; j < 4; ++j) acc[i][j] = floatx4{0.f, 0.f, 0.f, 0.f};

    const bf16_t* Abase = A + (size_t)tm * K;
    const bf16_t* Bbase = B + (size_t)tn * K;
    const int sw = l16 & 7;

    for (int kk = 0; kk < K; kk += 64) {
#pragma unroll
        for (int it = 0; it < 4; ++it) {
            int chunk = it * 256 + tid;
            int r = chunk >> 3, c = chunk & 7;
            int c2 = c ^ (r & 7);
            async16(Abase + r * K + kk + c2 * 8, As + (it * 256 + wave * 64) * 8);
            async16(Bbase + r * K + kk + c2 * 8, Bs + (it * 256 + wave * 64) * 8);
        }
        __syncthreads();
#pragma unroll
        for (int ks = 0; ks < 2; ++ks) {
            bf16x8 af[4], bf[4];
#pragma unroll
            for (int mt = 0; mt < 4; ++mt)
                af[mt] = *(const bf16x8*)(As + (wm + mt * 16 + l16) * 64 +
                                          ((ks * 4 + quad) ^ sw) * 8);
#pragma unroll
            for (int nt = 0; nt < 4; ++nt)
                bf[nt] = *(const bf16x8*)(Bs + (wn + nt * 16 + l16) * 64 +
                                          ((ks * 4 + quad) ^ sw) * 8);
#pragma unroll
            for (int mt = 0; mt < 4; ++mt)
#pragma unroll
                for (int nt = 0; nt < 4; ++nt)
                    acc[mt][nt] = __builtin_amdgcn_mfma_f32_16x16x32_bf16(af[mt], bf[nt],
                                                                          acc[mt][nt], 0, 0, 0);
        }
        __syncthreads();
    }
#pragma unroll
    for (int mt = 0; mt < 4; ++mt)
#pragma unroll
        for (int nt = 0; nt < 4; ++nt)
#pragma unroll
            for (int r = 0; r < 4; ++r) {
                int row = tm + wm + mt * 16 + quad * 4 + r;
                int col = tn + wn + nt * 16 + l16;
                float v;
                if (vmode) v = acc[mt][nt][r] + bv[row];
                else if (col < 2048) v = (acc[mt][nt][r] + bq[col]) * SL2E;  // Q prescaled
                else v = acc[mt][nt][r] + bk[col - 2048];
                Cb[(size_t)row * ldc + col] = (bf16_t)v;
            }
}

// ---------- O-projection GEMM (fp32 out + bias) ----------
__global__ __launch_bounds__(256) void gemm_out(const bf16_t* __restrict__ A,
                                                const bf16_t* __restrict__ B,
                                                const float* __restrict__ bias,
                                                float* __restrict__ Cf,
                                                int K, int ldc) {
    __shared__ bf16_t As[128 * 64];
    __shared__ bf16_t Bs[128 * 64];
    const int tid = threadIdx.x;
    const int wave = tid >> 6, lane = tid & 63;
    const int quad = lane >> 4, l16 = lane & 15;
    const int wm = (wave >> 1) * 64, wn = (wave & 1) * 64;
    const int tm = blockIdx.x * 128, tn = blockIdx.y * 128;

    floatx4 acc[4][4];
#pragma unroll
    for (int i = 0; i < 4; ++i)
#pragma unroll
        for (int j = 0; j < 4; ++j) acc[i][j] = floatx4{0.f, 0.f, 0.f, 0.f};

    const bf16_t* Abase = A + (size_t)tm * K;
    const bf16_t* Bbase = B + (size_t)tn * K;
    const int sw = l16 & 7;

    for (int kk = 0; kk < K; kk += 64) {
#pragma unroll
        for (int it = 0; it < 4; ++it) {
            int chunk = it * 256 + tid;
            int r = chunk >> 3, c = chunk & 7;
            int c2 = c ^ (r & 7);
            async16(Abase + r * K + kk + c2 * 8, As + (it * 256 + wave * 64) * 8);
            async16(Bbase + r * K + kk + c2 * 8, Bs + (it * 256 + wave * 64) * 8);
        }
        __syncthreads();
#pragma unroll
        for (int ks = 0; ks < 2; ++ks) {
            bf16x8 af[4], bf[4];
#pragma unroll
            for (int mt = 0; mt < 4; ++mt)
                af[mt] = *(const bf16x8*)(As + (wm + mt * 16 + l16) * 64 +
                                          ((ks * 4 + quad) ^ sw) * 8);
#pragma unroll
            for (int nt = 0; nt < 4; ++nt)
                bf[nt] = *(const bf16x8*)(Bs + (wn + nt * 16 + l16) * 64 +
                                          ((ks * 4 + quad) ^ sw) * 8);
#pragma unroll
            for (int mt = 0; mt < 4; ++mt)
#pragma unroll
                for (int nt = 0; nt < 4; ++nt)
                    acc[mt][nt] = __builtin_amdgcn_mfma_f32_16x16x32_bf16(af[mt], bf[nt],
                                                                          acc[mt][nt], 0, 0, 0);
        }
        __syncthreads();
    }
#pragma unroll
    for (int mt = 0; mt < 4; ++mt)
#pragma unroll
        for (int nt = 0; nt < 4; ++nt)
#pragma unroll
            for (int r = 0; r < 4; ++r) {
                int row = tm + wm + mt * 16 + quad * 4 + r;
                int col = tn + wn + nt * 16 + l16;
                Cf[(size_t)row * ldc + col] = acc[mt][nt][r] + bias[col];
            }
}

// ---------- flash attention: 128 q/block, no-max softmax, double-buffered ----
// 4 waves = (wq: 2 x 64q) x (wk: 2 x 32keys). Each wave holds TWO 32-q groups:
// qf[2][8] in VGPRs, Oacc[2][4] f32x16 in AGPRs (MFMA-only). QK/softmax run
// per-g (sf stays 16 VGPR); PV shares each V-fragment ds_read across both g.
// DS reads 24/wave-kt for 2x the FLOPs of R7; staging & barriers unchanged
// per kt -> MFMA:overhead ratio ~2x. Grid 512 = exactly 2 blocks/CU, 1 gen.
#define FA_BUF (64 * 128 + 128 * 64)  // 16384 bf16 = 32 KB per buffer
__global__ __launch_bounds__(256, 2) void flash_attn(const bf16_t* __restrict__ Qp,
                                                     const bf16_t* __restrict__ Kp,
                                                     const bf16_t* __restrict__ Vt,
                                                     bf16_t* __restrict__ O) {
    __shared__ bf16_t smem[2 * FA_BUF];  // 64 KB
    const int tid = threadIdx.x;
    const int wv = tid >> 6, lane = tid & 63;
    const int hi = lane >> 5, l32 = lane & 31;
    const int wq = wv >> 1, wk = wv & 1;
    const int LD = 4096, T = 4096, S = 2048, HO = 2048;

    // XCD decode over 512 blocks: gid%8 pins (h,b)-group set to one XCD
    const int gid = blockIdx.x;
    const int kq = gid >> 3;                     // 0..63
    const int qt = kq & 15;                      // q-tile (128q) 0..15
    const int grp = (gid & 7) + 8 * (kq >> 4);   // group 0..31
    const int hd = grp & 15, bt = grp >> 4;

    const int qrow0 = bt * S + qt * 128;
    const int krow0 = bt * S;
    const int hoff = hd * 128;
    const int sw7 = l32 & 7;

    // Q B-frags for the wave's two 32-q groups (Q already scaled by SL2E)
    bf16x8 qf[2][8];
#pragma unroll
    for (int g = 0; g < 2; ++g) {
        const bf16_t* qptr = Qp + (size_t)(qrow0 + wq * 64 + g * 32 + l32) * LD + hoff + hi * 8;
#pragma unroll
        for (int ks = 0; ks < 8; ++ks) qf[g][ks] = *(const bf16x8*)(qptr + ks * 16);
    }

    float l_i[2] = {0.f, 0.f};
    f32x16 Oacc[2][4];  // O^T partials, col q = l32 (AGPR-resident, MFMA-only)
#pragma unroll
    for (int g = 0; g < 2; ++g)
#pragma unroll
        for (int dt = 0; dt < 4; ++dt)
#pragma unroll
            for (int r = 0; r < 16; ++r) Oacc[g][dt][r] = 0.f;

    auto stage = [&](int kt, int b) {
        int kb = krow0 + kt * 64;
        bf16_t* Ks = smem + b * FA_BUF;
        bf16_t* Vts = Ks + 64 * 128;
#pragma unroll
        for (int it = 0; it < 4; ++it) {
            int chunk = it * 256 + tid;
            int r = chunk >> 4, c = chunk & 15;
            int c2 = c ^ (r & 7);
            async16(Kp + (size_t)(kb + r) * LD + hoff + c2 * 8, Ks + chunk * 8);
        }
#pragma unroll
        for (int it = 0; it < 4; ++it) {
            int chunk = it * 256 + tid;
            int r = chunk >> 3, c = chunk & 7;
            int c2 = c ^ (r & 7);
            async16(Vt + (size_t)(hoff + r) * T + kb + c2 * 8, Vts + chunk * 8);
        }
    };

    stage(0, 0);
    for (int kt = 0; kt < 32; ++kt) {
        const int cur = kt & 1;
        __syncthreads();
        if (kt + 1 < 32) stage(kt + 1, cur ^ 1);

        const bf16_t* Ks = smem + cur * FA_BUF;
        const bf16_t* Vts = Ks + 64 * 128;

        uint32_t pk[2][8];
#pragma unroll
        for (int g = 0; g < 2; ++g) {
            // S^T = K Q^T for this g: C row=key, col=q=l32
            f32x16 sf;
#pragma unroll
            for (int r = 0; r < 16; ++r) sf[r] = 0.f;
#pragma unroll
            for (int ks = 0; ks < 8; ++ks) {
                bf16x8 a = *(const bf16x8*)(Ks + (wk * 32 + l32) * 128 +
                                            ((2 * ks + hi) ^ sw7) * 8);
                sf = __builtin_amdgcn_mfma_f32_32x32x16_bf16(a, qf[g][ks], sf, 0, 0, 0);
            }
            // no-max softmax (Q prescaled: p = 2^s directly)
            float rs0 = 0.f, rs1 = 0.f;
#pragma unroll
            for (int a4 = 0; a4 < 4; ++a4) {
                float p0 = exp2f(sf[4 * a4 + 0]);
                float p1 = exp2f(sf[4 * a4 + 1]);
                float p2 = exp2f(sf[4 * a4 + 2]);
                float p3 = exp2f(sf[4 * a4 + 3]);
                rs0 += p0 + p1;
                rs1 += p2 + p3;
                pk[g][a4 * 2 + 0] = pack2(p0, p1);
                pk[g][a4 * 2 + 1] = pack2(p2, p3);
            }
            l_i[g] += rs0 + rs1;
        }

        // O^T += V^T P^T; each V-frag ds_read feeds BOTH q-groups' MFMA
#pragma unroll
        for (int s = 0; s < 2; ++s) {
            union { uint32_t u[4]; bf16x8 v; } w[2];
#pragma unroll
            for (int g = 0; g < 2; ++g) {
                uint32_t r0 = (uint32_t)__shfl_xor((int)pk[g][4 * s + 0], 32);
                uint32_t r1 = (uint32_t)__shfl_xor((int)pk[g][4 * s + 1], 32);
                uint32_t r2 = (uint32_t)__shfl_xor((int)pk[g][4 * s + 2], 32);
                uint32_t r3 = (uint32_t)__shfl_xor((int)pk[g][4 * s + 3], 32);
                w[g].u[0] = hi ? r2 : pk[g][4 * s + 0];
                w[g].u[1] = hi ? r3 : pk[g][4 * s + 1];
                w[g].u[2] = hi ? pk[g][4 * s + 2] : r0;
                w[g].u[3] = hi ? pk[g][4 * s + 3] : r1;
            }
#pragma unroll
            for (int dt = 0; dt < 4; ++dt) {
                bf16x8 av = *(const bf16x8*)(Vts + (dt * 32 + l32) * 64 +
                                             ((4 * wk + 2 * s + hi) ^ sw7) * 8);
                Oacc[0][dt] = __builtin_amdgcn_mfma_f32_32x32x16_bf16(av, w[0].v, Oacc[0][dt], 0, 0, 0);
                Oacc[1][dt] = __builtin_amdgcn_mfma_f32_32x32x16_bf16(av, w[1].v, Oacc[1][dt], 0, 0, 0);
            }
        }
    }

    // ---- merge k-waves; normalize; transpose; store ----
    __syncthreads();  // main loop done; smem reusable
    float* ml = (float*)smem;  // [4 waves][2 g][32 q]
#pragma unroll
    for (int g = 0; g < 2; ++g) l_i[g] += __shfl_xor(l_i[g], 32);
    if (hi == 0) {
        ml[(wv * 2 + 0) * 32 + l32] = l_i[0];
        ml[(wv * 2 + 1) * 32 + l32] = l_i[1];
    }
    __syncthreads();
    float linv[2];
#pragma unroll
    for (int g = 0; g < 2; ++g)
        linv[g] = 1.0f / (l_i[g] + ml[((wv ^ 1) * 2 + g) * 32 + l32]);
    __syncthreads();  // ml consumed; reuse full 64 KB for O-sum

    float* Op = (float*)smem;  // [2 wq][2 g][128 d][32 q] fp32 = 64 KB
    if (wk == 1) {
#pragma unroll
        for (int g = 0; g < 2; ++g)
#pragma unroll
            for (int dt = 0; dt < 4; ++dt)
#pragma unroll
                for (int r = 0; r < 16; ++r) {
                    int d = dt * 32 + (r & 3) + 8 * (r >> 2) + 4 * hi;
                    Op[((wq * 2 + g) * 128 + d) * 32 + l32] = Oacc[g][dt][r];
                }
    }
    __syncthreads();
    if (wk == 0) {
#pragma unroll
        for (int g = 0; g < 2; ++g)
#pragma unroll
            for (int dt = 0; dt < 4; ++dt)
#pragma unroll
                for (int r = 0; r < 16; ++r) {
                    int d = dt * 32 + (r & 3) + 8 * (r >> 2) + 4 * hi;
                    Oacc[g][dt][r] = (Oacc[g][dt][r] +
                                      Op[((wq * 2 + g) * 128 + d) * 32 + l32]) * linv[g];
                }
    }
    __syncthreads();  // Op consumed; reuse first 32 KB for transpose staging

    if (wk == 0) {
        // O^T -> O rows via rotated-column LDS staging (per wq: 64 rows x 64 u32)
        uint32_t* Os = (uint32_t*)smem + wq * 4096;
#pragma unroll
        for (int g = 0; g < 2; ++g)
#pragma unroll
            for (int dt = 0; dt < 4; ++dt)
#pragma unroll
                for (int a4 = 0; a4 < 4; ++a4) {
                    uint32_t q0 = pack2(Oacc[g][dt][4 * a4 + 0], Oacc[g][dt][4 * a4 + 1]);
                    uint32_t q1 = pack2(Oacc[g][dt][4 * a4 + 2], Oacc[g][dt][4 * a4 + 3]);
                    int d2 = 16 * dt + 4 * a4 + 2 * hi;
                    int row = g * 32 + l32;
                    Os[row * 64 + ((d2 + 2 * l32) & 63)] = q0;
                    Os[row * 64 + ((d2 + 1 + 2 * l32) & 63)] = q1;
                }
    }
    __syncthreads();
    // all 4 waves store: 128 rows / 4 waves
#pragma unroll
    for (int r2 = 0; r2 < 32; ++r2) {
        int rr = wv * 32 + r2;            // 0..127
        int wqs = rr >> 6, r = rr & 63;
        uint32_t v = ((uint32_t*)smem)[wqs * 4096 + r * 64 + ((lane + 2 * r) & 63)];
        uint32_t* orow = (uint32_t*)(O + (size_t)(qrow0 + wqs * 64 + r) * HO + hoff);
        orow[lane] = v;
    }
}

// ---------- launch ----------
extern "C" void kernel_launch(void* const* d_in, const int* in_sizes, int n_in,
                              void* d_out, int out_size, void* d_ws, size_t ws_size,
                              hipStream_t stream) {
    const float* x  = (const float*)d_in[0];
    const float* Wq = (const float*)d_in[1];
    const float* bq = (const float*)d_in[2];
    const float* Wk = (const float*)d_in[3];
    const float* bk = (const float*)d_in[4];
    const float* Wv = (const float*)d_in[5];
    const float* bv = (const float*)d_in[6];
    const float* Wo = (const float*)d_in[7];
    const float* bo = (const float*)d_in[8];
    float* out = (float*)d_out;

    const int T = 4096;          // B*S tokens
    const int H = 2048;          // hidden
    bf16_t* ws  = (bf16_t*)d_ws;
    bf16_t* xb  = ws;                         // T*H
    bf16_t* wqb = xb  + (size_t)T * H;        // H*H x4, contiguous after xb
    bf16_t* wvb = wqb + 2 * (size_t)H * H;
    bf16_t* wob = wvb + (size_t)H * H;
    bf16_t* QKb = wob + (size_t)H * H;        // T x 4096 (Q cols 0..2047 prescaled, K rest)
    bf16_t* Vtb = QKb + (size_t)T * 2 * H;    // H x T (V transposed: feature-major)
    bf16_t* Ab  = Vtb + (size_t)H * T;        // T*H attention context
    size_t need = (size_t)(Ab + (size_t)T * H - ws) * sizeof(bf16_t);
    if (ws_size < need) return;

    cvt_all<<<12288, 256, 0, stream>>>(x, Wq, Wk, Wv, Wo, ws);

    gemm_qkv<<<1536, 256, 0, stream>>>(xb, wqb, wvb, bq, bk, bv, QKb, Vtb);

    flash_attn<<<512, 256, 0, stream>>>(QKb, QKb + H, Vtb, Ab);

    dim3 go(T / 128, H / 128);
    gemm_out<<<go, 256, 0, stream>>>(Ab, wob, bo, out, H, H);
}

// Round 9
// 428.571 us; speedup vs baseline: 1.0656x; 1.0656x over previous
//
#include <hip/hip_runtime.h>
#include <hip/hip_bf16.h>
#include <stdint.h>

// ---------- types ----------
typedef __bf16 bf16_t;
typedef __attribute__((ext_vector_type(8))) __bf16 bf16x8;   // MFMA A/B frag (4 VGPR)
typedef __attribute__((ext_vector_type(4))) float floatx4;   // 16x16 C frag
typedef __attribute__((ext_vector_type(16))) float f32x16;   // 32x32 C frag

typedef __attribute__((address_space(1))) const unsigned int gu32_t;
typedef __attribute__((address_space(3))) unsigned int lu32_t;

#define SL2E 0.12753102149f  // log2(e)/sqrt(128), folded into Q at projection

// async global->LDS, 16B per lane; LDS dest = wave-uniform base + lane*16
__device__ __forceinline__ void async16(const void* g, void* l) {
    __builtin_amdgcn_global_load_lds((gu32_t*)g, (lu32_t*)l, 16, 0, 0);
}

__device__ __forceinline__ uint32_t pack2(float lo, float hi) {
    union { bf16_t h[2]; uint32_t u; } cv;
    cv.h[0] = (bf16_t)lo; cv.h[1] = (bf16_t)hi;
    return cv.u;
}

// ---------- fp32 -> bf16: x + 4 weights in ONE dispatch ----------
__global__ __launch_bounds__(256) void cvt_all(const float* __restrict__ x,
                                               const float* __restrict__ w0,
                                               const float* __restrict__ w1,
                                               const float* __restrict__ w2,
                                               const float* __restrict__ w3,
                                               bf16_t* __restrict__ out) {
    int b = blockIdx.x;
    const float* in;
    if (b < 4096) {
        in = x + (size_t)b * 2048;
    } else {
        int t = b - 4096;
        const float* wsrc[4] = {w0, w1, w2, w3};
        in = wsrc[t >> 11] + (size_t)(t & 2047) * 2048;
    }
    bf16_t* o = out + (size_t)b * 2048;
    int i = threadIdx.x * 8;
    float4 a = *(const float4*)(in + i);
    float4 c = *(const float4*)(in + i + 4);
    bf16x8 v;
    v[0] = (bf16_t)a.x; v[1] = (bf16_t)a.y; v[2] = (bf16_t)a.z; v[3] = (bf16_t)a.w;
    v[4] = (bf16_t)c.x; v[5] = (bf16_t)c.y; v[6] = (bf16_t)c.z; v[7] = (bf16_t)c.w;
    *(bf16x8*)(o + i) = v;
}

// ---------- fused QK + V^T projection, DOUBLE-BUFFERED K-loop ----------
// bid < 1024: QK tile -> QKb (Q cols prescaled by SL2E, bias folded); else
// V^T tile -> Vtb. One barrier per K-iter; stage(ki+1) issued right after the
// barrier so its vmcnt(0) drain (next barrier) waits on loads a full compute
// phase old -- the R6->R7 flash transform applied to the GEMM (R8: 26% MFU,
// ~40% barrier-drain stall).
#define GB (128 * 64)  // bf16 elems per As or Bs tile (16 KB)
__global__ __launch_bounds__(256, 2) void gemm_qkv(const bf16_t* __restrict__ xb,
                                                   const bf16_t* __restrict__ wqk,
                                                   const bf16_t* __restrict__ wv,
                                                   const float* __restrict__ bq,
                                                   const float* __restrict__ bk,
                                                   const float* __restrict__ bv,
                                                   bf16_t* __restrict__ QKb,
                                                   bf16_t* __restrict__ Vtb) {
    __shared__ bf16_t smem[4 * GB];  // [buf][As|Bs] = 64 KB
    const int tid = threadIdx.x;
    const int wave = tid >> 6, lane = tid & 63;
    const int quad = lane >> 4, l16 = lane & 15;
    const int wm = (wave >> 1) * 64, wn = (wave & 1) * 64;

    const int bid = blockIdx.x;
    const bool vmode = bid >= 1024;
    int tm, tn;
    const bf16_t *A, *B;
    bf16_t* Cb;
    if (!vmode) { tm = (bid & 31) * 128; tn = (bid >> 5) * 128; A = xb; B = wqk; Cb = QKb; }
    else { int vb = bid - 1024; tm = (vb & 15) * 128; tn = (vb >> 4) * 128; A = wv; B = xb; Cb = Vtb; }
    const int K = 2048, ldc = 4096;

    floatx4 acc[4][4];
#pragma unroll
    for (int i = 0; i < 4; ++i)
#pragma unroll
        for (int j = 0; j < 4; ++j) acc[i][j] = floatx4{0.f, 0.f, 0.f, 0.f};

    const bf16_t* Abase = A + (size_t)tm * K;
    const bf16_t* Bbase = B + (size_t)tn * K;
    const int sw = l16 & 7;

    auto stageAB = [&](int kk, int b) {
        bf16_t* As = smem + b * 2 * GB;
        bf16_t* Bs = As + GB;
#pragma unroll
        for (int it = 0; it < 4; ++it) {
            int chunk = it * 256 + tid;
            int r = chunk >> 3, c = chunk & 7;
            int c2 = c ^ (r & 7);
            async16(Abase + r * K + kk + c2 * 8, As + (it * 256 + wave * 64) * 8);
            async16(Bbase + r * K + kk + c2 * 8, Bs + (it * 256 + wave * 64) * 8);
        }
    };

    stageAB(0, 0);
    for (int ki = 0; ki < 32; ++ki) {
        const int cur = ki & 1;
        __syncthreads();
        if (ki + 1 < 32) stageAB((ki + 1) * 64, cur ^ 1);
        const bf16_t* As = smem + cur * 2 * GB;
        const bf16_t* Bs = As + GB;
#pragma unroll
        for (int ks = 0; ks < 2; ++ks) {
            bf16x8 af[4], bf[4];
#pragma unroll
            for (int mt = 0; mt < 4; ++mt)
                af[mt] = *(const bf16x8*)(As + (wm + mt * 16 + l16) * 64 +
                                          ((ks * 4 + quad) ^ sw) * 8);
#pragma unroll
            for (int nt = 0; nt < 4; ++nt)
                bf[nt] = *(const bf16x8*)(Bs + (wn + nt * 16 + l16) * 64 +
                                          ((ks * 4 + quad) ^ sw) * 8);
#pragma unroll
            for (int mt = 0; mt < 4; ++mt)
#pragma unroll
                for (int nt = 0; nt < 4; ++nt)
                    acc[mt][nt] = __builtin_amdgcn_mfma_f32_16x16x32_bf16(af[mt], bf[nt],
                                                                          acc[mt][nt], 0, 0, 0);
        }
    }
#pragma unroll
    for (int mt = 0; mt < 4; ++mt)
#pragma unroll
        for (int nt = 0; nt < 4; ++nt)
#pragma unroll
            for (int r = 0; r < 4; ++r) {
                int row = tm + wm + mt * 16 + quad * 4 + r;
                int col = tn + wn + nt * 16 + l16;
                float v;
                if (vmode) v = acc[mt][nt][r] + bv[row];
                else if (col < 2048) v = (acc[mt][nt][r] + bq[col]) * SL2E;  // Q prescaled
                else v = acc[mt][nt][r] + bk[col - 2048];
                Cb[(size_t)row * ldc + col] = (bf16_t)v;
            }
}

// ---------- O-projection GEMM (fp32 out + bias), double-buffered ----------
__global__ __launch_bounds__(256, 2) void gemm_out(const bf16_t* __restrict__ A,
                                                   const bf16_t* __restrict__ B,
                                                   const float* __restrict__ bias,
                                                   float* __restrict__ Cf,
                                                   int K, int ldc) {
    __shared__ bf16_t smem[4 * GB];  // 64 KB
    const int tid = threadIdx.x;
    const int wave = tid >> 6, lane = tid & 63;
    const int quad = lane >> 4, l16 = lane & 15;
    const int wm = (wave >> 1) * 64, wn = (wave & 1) * 64;
    const int tm = blockIdx.x * 128, tn = blockIdx.y * 128;

    floatx4 acc[4][4];
#pragma unroll
    for (int i = 0; i < 4; ++i)
#pragma unroll
        for (int j = 0; j < 4; ++j) acc[i][j] = floatx4{0.f, 0.f, 0.f, 0.f};

    const bf16_t* Abase = A + (size_t)tm * K;
    const bf16_t* Bbase = B + (size_t)tn * K;
    const int sw = l16 & 7;
    const int nIter = K / 64;

    auto stageAB = [&](int kk, int b) {
        bf16_t* As = smem + b * 2 * GB;
        bf16_t* Bs = As + GB;
#pragma unroll
        for (int it = 0; it < 4; ++it) {
            int chunk = it * 256 + tid;
            int r = chunk >> 3, c = chunk & 7;
            int c2 = c ^ (r & 7);
            async16(Abase + r * K + kk + c2 * 8, As + (it * 256 + wave * 64) * 8);
            async16(Bbase + r * K + kk + c2 * 8, Bs + (it * 256 + wave * 64) * 8);
        }
    };

    stageAB(0, 0);
    for (int ki = 0; ki < nIter; ++ki) {
        const int cur = ki & 1;
        __syncthreads();
        if (ki + 1 < nIter) stageAB((ki + 1) * 64, cur ^ 1);
        const bf16_t* As = smem + cur * 2 * GB;
        const bf16_t* Bs = As + GB;
#pragma unroll
        for (int ks = 0; ks < 2; ++ks) {
            bf16x8 af[4], bf[4];
#pragma unroll
            for (int mt = 0; mt < 4; ++mt)
                af[mt] = *(const bf16x8*)(As + (wm + mt * 16 + l16) * 64 +
                                          ((ks * 4 + quad) ^ sw) * 8);
#pragma unroll
            for (int nt = 0; nt < 4; ++nt)
                bf[nt] = *(const bf16x8*)(Bs + (wn + nt * 16 + l16) * 64 +
                                          ((ks * 4 + quad) ^ sw) * 8);
#pragma unroll
            for (int mt = 0; mt < 4; ++mt)
#pragma unroll
                for (int nt = 0; nt < 4; ++nt)
                    acc[mt][nt] = __builtin_amdgcn_mfma_f32_16x16x32_bf16(af[mt], bf[nt],
                                                                          acc[mt][nt], 0, 0, 0);
        }
    }
#pragma unroll
    for (int mt = 0; mt < 4; ++mt)
#pragma unroll
        for (int nt = 0; nt < 4; ++nt)
#pragma unroll
            for (int r = 0; r < 4; ++r) {
                int row = tm + wm + mt * 16 + quad * 4 + r;
                int col = tn + wn + nt * 16 + l16;
                Cf[(size_t)row * ldc + col] = acc[mt][nt][r] + bias[col];
            }
}

// ---------- flash attention: R7 64q kernel (known 123.6 us), Q prescaled ----
// 4 waves = 2 q-halves x 2 k-halves, no-max softmax, double-buffered staging,
// XCD-swizzled 1D grid (1024 blocks). Only delta vs R7: p = exp2f(s) directly
// (SL2E folded into Q at projection).
#define FA_BUF (64 * 128 + 128 * 64)  // 16384 bf16 = 32 KB per buffer
__global__ __launch_bounds__(256, 2) void flash_attn(const bf16_t* __restrict__ Qp,
                                                     const bf16_t* __restrict__ Kp,
                                                     const bf16_t* __restrict__ Vt,
                                                     bf16_t* __restrict__ O) {
    __shared__ bf16_t smem[2 * FA_BUF];  // 64 KB
    const int tid = threadIdx.x;
    const int wv = tid >> 6, lane = tid & 63;
    const int hi = lane >> 5, l32 = lane & 31;
    const int wq = wv >> 1, wk = wv & 1;
    const int LD = 4096, T = 4096, S = 2048, HO = 2048;

    // XCD-aware decode: gid = (g%8) + 8*(q + 32*(g/8)), g = (h,b) in [0,32)
    const int gid = blockIdx.x;
    const int kq = gid >> 3;
    const int qt = kq & 31;                       // q-tile 0..31
    const int grp = (gid & 7) + 8 * (kq >> 5);    // group 0..31
    const int hd = grp & 15, bt = grp >> 4;

    const int qrow0 = bt * S + qt * 64;
    const int krow0 = bt * S;
    const int hoff = hd * 128;
    const int sw7 = l32 & 7;

    // Q B-frags: B[k][q=l32], k = 16*ks + 8*hi + j, for q-rows wq*32..+32
    bf16x8 qf[8];
    const bf16_t* qptr = Qp + (size_t)(qrow0 + wq * 32 + l32) * LD + hoff + hi * 8;
#pragma unroll
    for (int ks = 0; ks < 8; ++ks) qf[ks] = *(const bf16x8*)(qptr + ks * 16);

    float l_i = 0.f;   // linear softmax denominator partial
    f32x16 Oacc[4];    // O^T partial: rows d (128), col q = l32 (AGPR-resident)
#pragma unroll
    for (int dt = 0; dt < 4; ++dt)
#pragma unroll
        for (int r = 0; r < 16; ++r) Oacc[dt][r] = 0.f;

    auto stage = [&](int kt, int b) {
        int kb = krow0 + kt * 64;
        bf16_t* Ks = smem + b * FA_BUF;
        bf16_t* Vts = Ks + 64 * 128;
#pragma unroll
        for (int it = 0; it < 4; ++it) {
            int chunk = it * 256 + tid;
            int r = chunk >> 4, c = chunk & 15;
            int c2 = c ^ (r & 7);
            async16(Kp + (size_t)(kb + r) * LD + hoff + c2 * 8, Ks + chunk * 8);
        }
#pragma unroll
        for (int it = 0; it < 4; ++it) {
            int chunk = it * 256 + tid;
            int r = chunk >> 3, c = chunk & 7;
            int c2 = c ^ (r & 7);
            async16(Vt + (size_t)(hoff + r) * T + kb + c2 * 8, Vts + chunk * 8);
        }
    };

    stage(0, 0);
    for (int kt = 0; kt < 32; ++kt) {
        const int cur = kt & 1;
        __syncthreads();
        if (kt + 1 < 32) stage(kt + 1, cur ^ 1);

        const bf16_t* Ks = smem + cur * FA_BUF;
        const bf16_t* Vts = Ks + 64 * 128;

        // S^T = K Q^T over this wave's 32 keys: two independent 4-chains
        f32x16 sf0, sf1;
#pragma unroll
        for (int r = 0; r < 16; ++r) { sf0[r] = 0.f; sf1[r] = 0.f; }
#pragma unroll
        for (int ks = 0; ks < 4; ++ks) {
            bf16x8 a0 = *(const bf16x8*)(Ks + (wk * 32 + l32) * 128 +
                                         ((2 * ks + hi) ^ sw7) * 8);
            bf16x8 a1 = *(const bf16x8*)(Ks + (wk * 32 + l32) * 128 +
                                         ((2 * (ks + 4) + hi) ^ sw7) * 8);
            sf0 = __builtin_amdgcn_mfma_f32_32x32x16_bf16(a0, qf[ks], sf0, 0, 0, 0);
            sf1 = __builtin_amdgcn_mfma_f32_32x32x16_bf16(a1, qf[ks + 4], sf1, 0, 0, 0);
        }

        // no-max softmax (Q prescaled): p = 2^s
        float rs0 = 0.f, rs1 = 0.f;
        uint32_t pk[8];
#pragma unroll
        for (int a4 = 0; a4 < 4; ++a4) {
            float p0 = exp2f(sf0[4 * a4 + 0] + sf1[4 * a4 + 0]);
            float p1 = exp2f(sf0[4 * a4 + 1] + sf1[4 * a4 + 1]);
            float p2 = exp2f(sf0[4 * a4 + 2] + sf1[4 * a4 + 2]);
            float p3 = exp2f(sf0[4 * a4 + 3] + sf1[4 * a4 + 3]);
            rs0 += p0 + p1;
            rs1 += p2 + p3;
            pk[a4 * 2 + 0] = pack2(p0, p1);
            pk[a4 * 2 + 1] = pack2(p2, p3);
        }
        l_i += rs0 + rs1;

        // O^T += V^T P^T over this wave's 32 keys (2 steps of 16)
#pragma unroll
        for (int s = 0; s < 2; ++s) {
            uint32_t r0 = (uint32_t)__shfl_xor((int)pk[4 * s + 0], 32);
            uint32_t r1 = (uint32_t)__shfl_xor((int)pk[4 * s + 1], 32);
            uint32_t r2 = (uint32_t)__shfl_xor((int)pk[4 * s + 2], 32);
            uint32_t r3 = (uint32_t)__shfl_xor((int)pk[4 * s + 3], 32);
            union { uint32_t u[4]; bf16x8 v; } w;
            w.u[0] = hi ? r2 : pk[4 * s + 0];
            w.u[1] = hi ? r3 : pk[4 * s + 1];
            w.u[2] = hi ? pk[4 * s + 2] : r0;
            w.u[3] = hi ? pk[4 * s + 3] : r1;
#pragma unroll
            for (int dt = 0; dt < 4; ++dt) {
                bf16x8 a = *(const bf16x8*)(Vts + (dt * 32 + l32) * 64 +
                                            ((4 * wk + 2 * s + hi) ^ sw7) * 8);
                Oacc[dt] = __builtin_amdgcn_mfma_f32_32x32x16_bf16(a, w.v, Oacc[dt], 0, 0, 0);
            }
        }
    }

    // ---- merge the two k-waves of each wq: l = l0+l1, O = (O0+O1)/l ----
    __syncthreads();
    l_i += __shfl_xor(l_i, 32);
    float* ml = (float*)smem;    // [wave][32q]
    if (hi == 0) ml[wv * 32 + l32] = l_i;
    __syncthreads();
    float linv = 1.0f / (l_i + ml[(wv ^ 1) * 32 + l32]);
    __syncthreads();  // done reading ml; reuse buffer 0 (32 KB) for O-sum

    float* Op = (float*)smem;  // [2 wq][128 d][32 q] fp32 = 32 KB
    if (wk == 1) {
#pragma unroll
        for (int dt = 0; dt < 4; ++dt)
#pragma unroll
            for (int r = 0; r < 16; ++r) {
                int d = dt * 32 + (r & 3) + 8 * (r >> 2) + 4 * hi;
                Op[(wq * 128 + d) * 32 + l32] = Oacc[dt][r];
            }
    }
    __syncthreads();
    if (wk == 0) {
#pragma unroll
        for (int dt = 0; dt < 4; ++dt)
#pragma unroll
            for (int r = 0; r < 16; ++r) {
                int d = dt * 32 + (r & 3) + 8 * (r >> 2) + 4 * hi;
                Oacc[dt][r] = (Oacc[dt][r] + Op[(wq * 128 + d) * 32 + l32]) * linv;
            }
    }
    __syncthreads();  // Op consumed; reuse LDS for transpose staging

    if (wk == 0) {
        // O^T -> O transpose via LDS (per wq wave, 8 KB each), rotated cols
        uint32_t* Os = (uint32_t*)smem + wq * 2048;  // 32 q-rows x 64 u32
#pragma unroll
        for (int dt = 0; dt < 4; ++dt)
#pragma unroll
            for (int a4 = 0; a4 < 4; ++a4) {
                uint32_t q0 = pack2(Oacc[dt][4 * a4 + 0], Oacc[dt][4 * a4 + 1]);
                uint32_t q1 = pack2(Oacc[dt][4 * a4 + 2], Oacc[dt][4 * a4 + 3]);
                int d2 = 16 * dt + 4 * a4 + 2 * hi;
                Os[l32 * 64 + ((d2 + 2 * l32) & 63)] = q0;
                Os[l32 * 64 + ((d2 + 1 + 2 * l32) & 63)] = q1;
            }
#pragma unroll
        for (int r = 0; r < 32; ++r) {
            uint32_t v = Os[r * 64 + ((lane + 2 * r) & 63)];
            uint32_t* orow = (uint32_t*)(O + (size_t)(qrow0 + wq * 32 + r) * HO + hoff);
            orow[lane] = v;
        }
    }
}

// ---------- launch ----------
extern "C" void kernel_launch(void* const* d_in, const int* in_sizes, int n_in,
                              void* d_out, int out_size, void* d_ws, size_t ws_size,
                              hipStream_t stream) {
    const float* x  = (const float*)d_in[0];
    const float* Wq = (const float*)d_in[1];
    const float* bq = (const float*)d_in[2];
    const float* Wk = (const float*)d_in[3];
    const float* bk = (const float*)d_in[4];
    const float* Wv = (const float*)d_in[5];
    const float* bv = (const float*)d_in[6];
    const float* Wo = (const float*)d_in[7];
    const float* bo = (const float*)d_in[8];
    float* out = (float*)d_out;

    const int T = 4096;          // B*S tokens
    const int H = 2048;          // hidden
    bf16_t* ws  = (bf16_t*)d_ws;
    bf16_t* xb  = ws;                         // T*H
    bf16_t* wqb = xb  + (size_t)T * H;        // H*H x4, contiguous after xb
    bf16_t* wvb = wqb + 2 * (size_t)H * H;
    bf16_t* wob = wvb + (size_t)H * H;
    bf16_t* QKb = wob + (size_t)H * H;        // T x 4096 (Q cols 0..2047 prescaled, K rest)
    bf16_t* Vtb = QKb + (size_t)T * 2 * H;    // H x T (V transposed: feature-major)
    bf16_t* Ab  = Vtb + (size_t)H * T;        // T*H attention context
    size_t need = (size_t)(Ab + (size_t)T * H - ws) * sizeof(bf16_t);
    if (ws_size < need) return;

    cvt_all<<<12288, 256, 0, stream>>>(x, Wq, Wk, Wv, Wo, ws);

    gemm_qkv<<<1536, 256, 0, stream>>>(xb, wqb, wvb, bq, bk, bv, QKb, Vtb);

    flash_attn<<<1024, 256, 0, stream>>>(QKb, QKb + H, Vtb, Ab);

    dim3 go(T / 128, H / 128);
    gemm_out<<<go, 256, 0, stream>>>(Ab, wob, bo, out, H, H);
}